// Round 7
// baseline (501.154 us; speedup 1.0000x reference)
//
#include <hip/hip_runtime.h>
#include <cmath>

#define B_ 32
#define S_ 1024
#define D_ 256
#define K_ 1024
#define N_ (B_*S_)

// ---- output layout (float elements) ----
#define O_Q     0
#define O_LOSS  8388608
#define O_PERP  8388609
#define O_IDX   8388610
#define O_NW    8421378
#define O_NEW   8683522
#define O_NCS   8945666

// ---- workspace layout (bytes) ----
#define OFF_FH    0ull          // N*256*2 = 16777216 (f16 feats)
#define OFF_WH    16777216ull   // K*256*2 = 524288  (f16 weights)
#define OFF_BW    17301504ull   // K*8
#define OFF_BWF   17309696ull   // K*4
#define OFF_SAMP  17313792ull   // N*8
#define OFF_IDXF  17575936ull   // N*4
#define OFF_ENC   17707008ull   // N*4
#define OFF_CNT   17838080ull   // K*4 (zeroed)
#define OFF_SLOWC 17842176ull   // 64  (zeroed, same memset)
#define OFF_SLOWL 17842240ull   // N*4
#define OFF_LOSSP 17973312ull   // N*8
#define OFF_ROWL  18235456ull   // N*4
#define OFF_ST    18366528ull   // (K+1)*4
#define OFF_POS   18370688ull   // K*4
#define OFF_CSF   18374784ull   // K*4

#define MARGIN 1e-4f

typedef _Float16 f16x8 __attribute__((ext_vector_type(8)));
typedef float    f32x4 __attribute__((ext_vector_type(4)));

// offset arg must be a literal at Sema time -> fold k-offset into gp instead.
#define GL16(gp, lp) __builtin_amdgcn_global_load_lds( \
    (const __attribute__((address_space(1))) unsigned int*)(const void*)(gp), \
    (__attribute__((address_space(3))) unsigned int*)(void*)(lp), 16, 0, 0)

// ---------------- LN -> f16 feats -------------
__global__ void k_ln(const float* __restrict__ x, const float* __restrict__ gam,
                     const float* __restrict__ bet, _Float16* __restrict__ fh) {
    int lane = threadIdx.x & 63, wv = threadIdx.x >> 6;
    int n = blockIdx.x * 4 + wv;
    const float* row = x + (size_t)n * D_;
    double xv[4], gv[4], bv[4];
#pragma unroll
    for (int i = 0; i < 4; i++) {
        int d = lane + 64 * i;
        xv[i] = row[d]; gv[i] = gam[d]; bv[i] = bet[d];
    }
    double s = xv[0] + xv[1] + xv[2] + xv[3];
    for (int m = 32; m > 0; m >>= 1) s += __shfl_xor(s, m, 64);
    double mu = s / 256.0, vs = 0.0;
#pragma unroll
    for (int i = 0; i < 4; i++) { double c = xv[i] - mu; vs += c * c; }
    for (int m = 32; m > 0; m >>= 1) vs += __shfl_xor(vs, m, 64);
    double inv = 1.0 / sqrt(vs / 256.0 + 1e-5);
#pragma unroll
    for (int i = 0; i < 4; i++) {
        int d = lane + 64 * i;
        float ff = (float)((xv[i] - mu) * inv * gv[i] + bv[i]);
        fh[(size_t)n * D_ + d] = (_Float16)ff;
    }
}

// ---------------- ||w||^2 (f64) + f16 w -------------
__global__ void k_bw(const float* __restrict__ w, double* __restrict__ Bw,
                     float* __restrict__ Bwf, _Float16* __restrict__ wh) {
    int lane = threadIdx.x & 63, wv = threadIdx.x >> 6;
    int k = blockIdx.x * 4 + wv;
    double s = 0.0;
#pragma unroll
    for (int i = 0; i < 4; i++) {
        int d = lane + 64 * i;
        float v = w[(size_t)k * D_ + d];
        s += (double)v * (double)v;
        wh[(size_t)k * D_ + d] = (_Float16)v;
    }
    for (int m = 32; m > 0; m >>= 1) s += __shfl_xor(s, m, 64);
    if (lane == 0) { Bw[k] = s; Bwf[k] = (float)s; }
}

// ---------------- Phase 1: f16 MFMA GEMM + fused top-2 -------------
// 1024 blocks x 256 thr (4 waves). Block = 128 rows x 256 codes (chunk=bIdx&3).
// Wave w: 128 rows x codes [w*64, w*64+64) => 32 MFMA per ks. K=256, BK=32, 8 ks.
// global_load_lds dwordx4 staging, packed double-buffered LDS (48 KB).
__launch_bounds__(256, 3)
__global__ void k_phase1(const _Float16* __restrict__ fh, const _Float16* __restrict__ wh,
                         const float* __restrict__ Bwf, float* __restrict__ pq) {
    __shared__ __align__(16) _Float16 sA[2][128][32];
    __shared__ __align__(16) _Float16 sB[2][256][32];

    const int tid = threadIdx.x;
    const int lane = tid & 63;
    const int w = tid >> 6;        // wave 0..3
    const int l15 = lane & 15;
    const int g = lane >> 4;       // 0..3
    const int chunk = blockIdx.x & 3;
    const int row0 = (blockIdx.x >> 2) * 128;
    const int c0 = chunk * 256;

    // staging: lane l -> LDS offset l*16B => row base+(l>>2), col (l&3)*8
    const int srow = lane >> 2;
    const int scol = (lane & 3) * 8;
    const _Float16* ga0 = fh + (size_t)(row0 + w * 32 + srow) * 256 + scol;   // rows w*32..+16
    const _Float16* ga1 = ga0 + 16 * 256;                                     // rows +16..+32
    const _Float16* gb0 = wh + (size_t)(c0 + w * 64 + srow) * 256 + scol;     // codes w*64..

    f32x4 acc[8][4];
#pragma unroll
    for (int a = 0; a < 8; a++)
#pragma unroll
        for (int b = 0; b < 4; b++) acc[a][b] = (f32x4){0.f, 0.f, 0.f, 0.f};

    // preload ks=0
    GL16(ga0, &sA[0][w * 32][0]);
    GL16(ga1, &sA[0][w * 32 + 16][0]);
    GL16(gb0,         &sB[0][w * 64][0]);
    GL16(gb0 + 4096,  &sB[0][w * 64 + 16][0]);
    GL16(gb0 + 8192,  &sB[0][w * 64 + 32][0]);
    GL16(gb0 + 12288, &sB[0][w * 64 + 48][0]);

#pragma unroll
    for (int ks = 0; ks < 8; ks++) {
        __syncthreads();   // barrier drain => buf[cur] staging complete
        if (ks < 7) {
            const int buf = (ks + 1) & 1;
            const int eoff = (ks + 1) * 32;   // element offset within row
            GL16(ga0 + eoff, &sA[buf][w * 32][0]);
            GL16(ga1 + eoff, &sA[buf][w * 32 + 16][0]);
            GL16(gb0 + eoff,         &sB[buf][w * 64][0]);
            GL16(gb0 + eoff + 4096,  &sB[buf][w * 64 + 16][0]);
            GL16(gb0 + eoff + 8192,  &sB[buf][w * 64 + 32][0]);
            GL16(gb0 + eoff + 12288, &sB[buf][w * 64 + 48][0]);
        }
        const int cur = ks & 1;
        f16x8 bfr[4];
#pragma unroll
        for (int fc = 0; fc < 4; fc++)
            bfr[fc] = *(const f16x8*)&sB[cur][w * 64 + fc * 16 + l15][g * 8];
#pragma unroll
        for (int fr = 0; fr < 8; fr++) {
            f16x8 af = *(const f16x8*)&sA[cur][fr * 16 + l15][g * 8];
#pragma unroll
            for (int fc = 0; fc < 4; fc++)
                acc[fr][fc] = __builtin_amdgcn_mfma_f32_16x16x32_f16(
                    af, bfr[fc], acc[fr][fc], 0, 0, 0);
        }
    }
    __syncthreads();   // all buf reads done before red (in sA) is written

    // epilogue: s = Bw - 2P, top-2 per row over this wave's 64 codes
    float bwv[4];
#pragma unroll
    for (int fc = 0; fc < 4; fc++) bwv[fc] = Bwf[c0 + w * 64 + fc * 16 + l15];
    float* red = (float*)&sA[0][0][0];   // 4 waves x 128 rows x 3 = 6 KB
#pragma unroll
    for (int fr = 0; fr < 8; fr++) {
#pragma unroll
        for (int r = 0; r < 4; r++) {
            float m1 = 3e38f, m2 = 3e38f; int c1 = 0x7fffffff;
#pragma unroll
            for (int fc = 0; fc < 4; fc++) {
                float sv = fmaf(-2.0f, acc[fr][fc][r], bwv[fc]);
                int c = c0 + w * 64 + fc * 16 + l15;
                if (sv < m1 || (sv == m1 && c < c1)) { m2 = m1; m1 = sv; c1 = c; }
                else if (sv < m2) m2 = sv;
            }
#pragma unroll
            for (int msk = 1; msk <= 8; msk <<= 1) {
                float om1 = __shfl_xor(m1, msk, 64);
                float om2 = __shfl_xor(m2, msk, 64);
                int   oc  = __shfl_xor(c1, msk, 64);
                if (om1 < m1 || (om1 == m1 && oc < c1)) {
                    m2 = (m1 < om2) ? m1 : om2; m1 = om1; c1 = oc;
                } else {
                    m2 = (om1 < m2) ? om1 : m2;
                }
            }
            if (l15 == 0) {
                int rl = fr * 16 + g * 4 + r;
                int base = (w * 128 + rl) * 3;
                red[base] = m1; red[base + 1] = m2; ((int*)red)[base + 2] = c1;
            }
        }
    }
    __syncthreads();
    if (tid < 128) {
        float M1 = 3e38f, M2 = 3e38f; int C1 = 0x7fffffff;
        for (int wv = 0; wv < 4; wv++) {   // ascending code order => tie-break OK
            int base = (wv * 128 + tid) * 3;
            float m1 = red[base], m2 = red[base + 1]; int c = ((int*)red)[base + 2];
            if (m1 < M1 || (m1 == M1 && c < C1)) {
                M2 = (M1 < m2) ? M1 : m2; M1 = m1; C1 = c;
            } else {
                M2 = (m1 < M2) ? m1 : M2;
            }
        }
        pq[chunk * N_ + row0 + tid] = M1;                    // pm1
        pq[4 * N_ + chunk * N_ + row0 + tid] = M2;           // pm2
        ((int*)pq)[8 * N_ + chunk * N_ + row0 + tid] = C1;   // pc1
    }
}

// ---------------- Phase 2: merge 4 chunk-partials + exact f64 verify ----
__global__ void k_phase2(const float* __restrict__ x, const float* __restrict__ gam,
                         const float* __restrict__ bet, const float* __restrict__ w,
                         const double* __restrict__ Bw, const float* __restrict__ pq,
                         double* __restrict__ sampled, int* __restrict__ idxf,
                         unsigned* __restrict__ slowC, int* __restrict__ slowL) {
    int lane = threadIdx.x & 63, wv = threadIdx.x >> 6;
    int n = blockIdx.x * 4 + wv;
    const float* pm1 = pq;
    const float* pm2 = pq + 4 * N_;
    const int*   pc1 = (const int*)pq + 8 * N_;
    float M1 = 3e38f, M2 = 3e38f; int C1 = 0x7fffffff;
#pragma unroll
    for (int c = 0; c < 4; c++) {
        float m1 = pm1[c * N_ + n], m2 = pm2[c * N_ + n]; int cc = pc1[c * N_ + n];
        if (m1 < M1 || (m1 == M1 && cc < C1)) {
            M2 = (M1 < m2) ? M1 : m2; M1 = m1; C1 = cc;
        } else {
            M2 = (m1 < M2) ? m1 : M2;
        }
    }
    if (M2 - M1 <= MARGIN) {
        if (lane == 0) { unsigned p = atomicAdd(slowC, 1u); slowL[p] = n; }
        return;
    }
    const float* row = x + (size_t)n * D_;
    double xv[4], gv[4], bv[4];
#pragma unroll
    for (int i = 0; i < 4; i++) {
        int d = lane + 64 * i;
        xv[i] = row[d]; gv[i] = gam[d]; bv[i] = bet[d];
    }
    double s = xv[0] + xv[1] + xv[2] + xv[3];
    for (int m = 32; m > 0; m >>= 1) s += __shfl_xor(s, m, 64);
    double mu = s / 256.0, vs = 0.0;
#pragma unroll
    for (int i = 0; i < 4; i++) { double c = xv[i] - mu; vs += c * c; }
    for (int m = 32; m > 0; m >>= 1) vs += __shfl_xor(vs, m, 64);
    double inv = 1.0 / sqrt(vs / 256.0 + 1e-5);
    double f[4], A = 0.0;
#pragma unroll
    for (int i = 0; i < 4; i++) {
        f[i] = (xv[i] - mu) * inv * gv[i] + bv[i];
        A += f[i] * f[i];
    }
    for (int m = 32; m > 0; m >>= 1) A += __shfl_xor(A, m, 64);

    const float* wr_ = w + (size_t)C1 * D_;
    double ss = 0.0;
#pragma unroll
    for (int i = 0; i < 4; i++) ss += f[i] * (double)wr_[lane + 64 * i];
    for (int m = 32; m > 0; m >>= 1) ss += __shfl_xor(ss, m, 64);
    if (lane == 0) { sampled[n] = (A + Bw[C1]) - 2.0 * ss; idxf[n] = C1; }
}

// ---------------- Slow rows: compacted exact f64 full scan -------------
__launch_bounds__(256)
__global__ void k_slow(const float* __restrict__ x, const float* __restrict__ gam,
                       const float* __restrict__ bet, const float* __restrict__ w,
                       const double* __restrict__ Bw,
                       const int* __restrict__ slowL, const unsigned* __restrict__ slowC,
                       double* __restrict__ sampled, int* __restrict__ idxf) {
    __shared__ double bmS[4];
    __shared__ int    bcS[4];
    int lane = threadIdx.x & 63, wv = threadIdx.x >> 6;
    int cnt = (int)*slowC;
    for (int it = blockIdx.x; it < cnt; it += gridDim.x) {
        int n = slowL[it];
        const float* row = x + (size_t)n * D_;
        float4 xv4 = *(const float4*)(row + lane * 4);
        float4 gv4 = *(const float4*)(gam + lane * 4);
        float4 bv4 = *(const float4*)(bet + lane * 4);
        double xv[4] = {(double)xv4.x, (double)xv4.y, (double)xv4.z, (double)xv4.w};
        double gv[4] = {(double)gv4.x, (double)gv4.y, (double)gv4.z, (double)gv4.w};
        double bv[4] = {(double)bv4.x, (double)bv4.y, (double)bv4.z, (double)bv4.w};
        double s = xv[0] + xv[1] + xv[2] + xv[3];
        for (int m = 32; m > 0; m >>= 1) s += __shfl_xor(s, m, 64);
        double mu = s / 256.0, vs = 0.0;
#pragma unroll
        for (int i = 0; i < 4; i++) { double c = xv[i] - mu; vs += c * c; }
        for (int m = 32; m > 0; m >>= 1) vs += __shfl_xor(vs, m, 64);
        double inv = 1.0 / sqrt(vs / 256.0 + 1e-5);
        double f[4], A = 0.0;
#pragma unroll
        for (int i = 0; i < 4; i++) {
            f[i] = (xv[i] - mu) * inv * gv[i] + bv[i];
            A += f[i] * f[i];
        }
        for (int m = 32; m > 0; m >>= 1) A += __shfl_xor(A, m, 64);

        double bm = 1.0e300; int bc = 0x7fffffff;
        int cbase = wv * 256;
#pragma unroll 2
        for (int c = cbase; c < cbase + 256; c++) {
            float4 w4 = *(const float4*)(w + (size_t)c * D_ + lane * 4);
            double ss = f[0] * (double)w4.x + f[1] * (double)w4.y
                      + f[2] * (double)w4.z + f[3] * (double)w4.w;
            for (int m = 32; m > 0; m >>= 1) ss += __shfl_xor(ss, m, 64);
            double dist = (A + Bw[c]) - 2.0 * ss;
            if (dist < bm) { bm = dist; bc = c; }
        }
        if (lane == 0) { bmS[wv] = bm; bcS[wv] = bc; }
        __syncthreads();
        if (threadIdx.x == 0) {
            double M = bmS[0]; int C = bcS[0];
            for (int i = 1; i < 4; i++)
                if (bmS[i] < M || (bmS[i] == M && bcS[i] < C)) { M = bmS[i]; C = bcS[i]; }
            sampled[n] = M; idxf[n] = C;
        }
        __syncthreads();
    }
}

// ---------------- stable argsort per batch row + enc gather -------------
__launch_bounds__(1024)
__global__ void k_sort(const double* __restrict__ sampled, const int* __restrict__ idxf,
                       int* __restrict__ enc) {
    __shared__ double val[1024];
    __shared__ int    sid[1024];
    int b = blockIdx.x, t = threadIdx.x;
    val[t] = sampled[(size_t)b * S_ + t];
    sid[t] = t;
    __syncthreads();
    for (int k = 2; k <= 1024; k <<= 1) {
        for (int j = k >> 1; j > 0; j >>= 1) {
            int p = t ^ j;
            if (p > t) {
                double v0 = val[t], v1 = val[p];
                int i0 = sid[t], i1 = sid[p];
                bool gtv = (v0 > v1) || (v0 == v1 && i0 > i1);
                bool asc = ((t & k) == 0);
                if (asc ? gtv : !gtv) {
                    val[t] = v1; val[p] = v0; sid[t] = i1; sid[p] = i0;
                }
            }
            __syncthreads();
        }
    }
    enc[(size_t)b * S_ + t] = idxf[sid[t]];   // faithful reference flat-index bug
}

// ---------------- gather: quantized out, idx out, counts, per-row loss -------------
__global__ void k_gather(const float* __restrict__ x, const float* __restrict__ w,
                         const int* __restrict__ enc, float* __restrict__ out,
                         unsigned* __restrict__ cnt, double* __restrict__ lossP) {
    int lane = threadIdx.x & 63, wv = threadIdx.x >> 6;
    int n = blockIdx.x * 4 + wv;
    int e = enc[n];
    const float* wr_ = w + (size_t)e * D_;
    const float* xr = x + (size_t)n * D_;
    float* qr = out + O_Q + (size_t)n * D_;
    double ls = 0.0;
#pragma unroll
    for (int i = 0; i < 4; i++) {
        int d = lane + 64 * i;
        float q = wr_[d], xv = xr[d];
        qr[d] = q;
        double df = (double)q - (double)xv;
        ls += df * df;
    }
    for (int m = 32; m > 0; m >>= 1) ls += __shfl_xor(ls, m, 64);
    if (lane == 0) {
        lossP[n] = ls;
        out[O_IDX + n] = (float)e;
        atomicAdd(&cnt[e], 1u);
    }
}

// ---------------- finalize (+ fused prefix scan for CSR) -------------
__launch_bounds__(1024)
__global__ void k_final(const unsigned* __restrict__ cnt, const float* __restrict__ ema_cs,
                        const double* __restrict__ lossP, float* __restrict__ out,
                        float* __restrict__ csf, int* __restrict__ starts,
                        int* __restrict__ pos) {
    __shared__ double red[1024];
    __shared__ int sc[1024];
    int t = threadIdx.x;
    int cv = (int)cnt[t];
    float cf = (float)cv;
    float cs0 = 0.99f * ema_cs[t] + 0.01f * cf;
    red[t] = (double)cs0;
    sc[t] = cv;
    __syncthreads();
    for (int s = 512; s > 0; s >>= 1) { if (t < s) red[t] += red[t + s]; __syncthreads(); }
    double ntot = red[0];
    __syncthreads();
    double c2 = ((double)cs0 + 1e-5) / (ntot + 1024.0 * 1e-5) * ntot;
    out[O_NCS + t] = (float)c2;
    csf[t] = (float)c2;
    double p = (double)cf / 32768.0;
    red[t] = -p * log(p + 1e-10);
    __syncthreads();
    for (int s = 512; s > 0; s >>= 1) { if (t < s) red[t] += red[t + s]; __syncthreads(); }
    double ent = red[0];
    __syncthreads();
    double ls = 0.0;
    for (int i = 0; i < 32; i++) ls += lossP[t + 1024 * i];
    red[t] = ls;
    __syncthreads();
    for (int s = 512; s > 0; s >>= 1) { if (t < s) red[t] += red[t + s]; __syncthreads(); }
    if (t == 0) {
        out[O_PERP] = (float)exp(ent);
        out[O_LOSS] = (float)(1.25 * red[0] / 8388608.0);
    }
    // prefix scan of counts -> starts/pos
    for (int off = 1; off < 1024; off <<= 1) {
        int add = (t >= off) ? sc[t - off] : 0;
        __syncthreads();
        sc[t] += add;
        __syncthreads();
    }
    int excl = sc[t] - cv;
    starts[t] = excl;
    pos[t] = excl;
    if (t == 1023) starts[1024] = sc[t];
}

__global__ void k_fill(const int* __restrict__ enc, int* __restrict__ pos,
                       int* __restrict__ rowl) {
    int n = blockIdx.x * 256 + threadIdx.x;
    int p = atomicAdd(&pos[enc[n]], 1);
    rowl[p] = n;
}

// ---------------- dw gather-sum + EMA + new_weight -------------
__global__ void k_dwsum(const float* __restrict__ x, const float* __restrict__ ema_w,
                        const int* __restrict__ rowl, const int* __restrict__ starts,
                        const float* __restrict__ csf, float* __restrict__ out) {
    int k = blockIdx.x, d = threadIdx.x;
    int s0 = starts[k], s1 = starts[k + 1];
    float acc = 0.0f;
    for (int i = s0; i < s1; i++) {
        int rr = rowl[i];
        acc += x[(size_t)rr * D_ + d];
    }
    size_t idx = (size_t)k * D_ + d;
    float ne = 0.99f * ema_w[idx] + 0.01f * acc;
    out[O_NEW + idx] = ne;
    out[O_NW + idx] = ne / csf[k];
}

extern "C" void kernel_launch(void* const* d_in, const int* in_sizes, int n_in,
                              void* d_out, int out_size, void* d_ws, size_t ws_size,
                              hipStream_t stream) {
    (void)in_sizes; (void)n_in; (void)out_size; (void)ws_size;
    const float* x      = (const float*)d_in[0];
    const float* w      = (const float*)d_in[1];
    const float* ema_w  = (const float*)d_in[2];
    const float* ema_cs = (const float*)d_in[3];
    const float* g      = (const float*)d_in[4];
    const float* bt     = (const float*)d_in[5];
    float* out = (float*)d_out;
    char* ws = (char*)d_ws;

    _Float16* fh = (_Float16*)(ws + OFF_FH);
    _Float16* wh = (_Float16*)(ws + OFF_WH);
    double* Bw   = (double*)(ws + OFF_BW);
    float*  Bwf  = (float*)(ws + OFF_BWF);
    double* samp = (double*)(ws + OFF_SAMP);
    int*    idxf = (int*)(ws + OFF_IDXF);
    int*    enc  = (int*)(ws + OFF_ENC);
    unsigned* cnt = (unsigned*)(ws + OFF_CNT);
    unsigned* slowC = (unsigned*)(ws + OFF_SLOWC);
    int*    slowL = (int*)(ws + OFF_SLOWL);
    double* lossP = (double*)(ws + OFF_LOSSP);
    int*    rowl = (int*)(ws + OFF_ROWL);
    int*    st   = (int*)(ws + OFF_ST);
    int*    pos  = (int*)(ws + OFF_POS);
    float*  csf  = (float*)(ws + OFF_CSF);

    (void)hipMemsetAsync(ws + OFF_CNT, 0, 4160, stream);   // cnt + slowC

    k_ln<<<N_ / 4, 256, 0, stream>>>(x, g, bt, fh);
    k_bw<<<K_ / 4, 256, 0, stream>>>(w, Bw, Bwf, wh);
    k_phase1<<<1024, 256, 0, stream>>>(fh, wh, Bwf, out);  // partials in out-Q (dead region)
    k_phase2<<<N_ / 4, 256, 0, stream>>>(x, g, bt, w, Bw, out, samp, idxf, slowC, slowL);
    k_slow<<<256, 256, 0, stream>>>(x, g, bt, w, Bw, slowL, slowC, samp, idxf);
    k_sort<<<B_, 1024, 0, stream>>>(samp, idxf, enc);
    k_gather<<<N_ / 4, 256, 0, stream>>>(x, w, enc, out, cnt, lossP);
    k_final<<<1, 1024, 0, stream>>>(cnt, ema_cs, lossP, out, csf, st, pos);
    k_fill<<<N_ / 256, 256, 0, stream>>>(enc, pos, rowl);
    k_dwsum<<<K_, 256, 0, stream>>>(x, ema_w, rowl, st, csf, out);
}

// Round 8
// 371.122 us; speedup vs baseline: 1.3504x; 1.3504x over previous
//
#include <hip/hip_runtime.h>
#include <cmath>

#define B_ 32
#define S_ 1024
#define D_ 256
#define K_ 1024
#define N_ (B_*S_)

// ---- output layout (float elements) ----
#define O_Q     0
#define O_LOSS  8388608
#define O_PERP  8388609
#define O_IDX   8388610
#define O_NW    8421378
#define O_NEW   8683522
#define O_NCS   8945666

// ---- workspace layout (bytes) ----
#define OFF_FH    0ull          // N*256*2 = 16777216 (f16 feats)
#define OFF_WH    16777216ull   // K*256*2 = 524288  (f16 weights)
#define OFF_BW    17301504ull   // K*8
#define OFF_BWF   17309696ull   // K*4
#define OFF_SAMP  17313792ull   // N*8
#define OFF_IDXF  17575936ull   // N*4
#define OFF_ENC   17707008ull   // N*4
#define OFF_CNT   17838080ull   // K*4 (zeroed)
#define OFF_SLOWC 17842176ull   // 64  (zeroed, same memset)
#define OFF_SLOWL 17842240ull   // N*4
#define OFF_LOSSP 17973312ull   // N*8

#define MARGIN 4e-5f

typedef _Float16 f16x8 __attribute__((ext_vector_type(8)));
typedef float    f32x4 __attribute__((ext_vector_type(4)));

// offset arg must be a literal at Sema time -> fold k-offset into gp instead.
#define GL16(gp, lp) __builtin_amdgcn_global_load_lds( \
    (const __attribute__((address_space(1))) unsigned int*)(const void*)(gp), \
    (__attribute__((address_space(3))) unsigned int*)(void*)(lp), 16, 0, 0)

// ---------------- fused: LN -> f16 feats  |  ||w||^2 + f16 w -------------
__global__ void k_pre(const float* __restrict__ x, const float* __restrict__ gam,
                      const float* __restrict__ bet, _Float16* __restrict__ fh,
                      const float* __restrict__ w, double* __restrict__ Bw,
                      float* __restrict__ Bwf, _Float16* __restrict__ wh) {
    int lane = threadIdx.x & 63, wv = threadIdx.x >> 6;
    if (blockIdx.x < N_ / 4) {
        int n = blockIdx.x * 4 + wv;
        const float* row = x + (size_t)n * D_;
        double xv[4], gv[4], bv[4];
#pragma unroll
        for (int i = 0; i < 4; i++) {
            int d = lane + 64 * i;
            xv[i] = row[d]; gv[i] = gam[d]; bv[i] = bet[d];
        }
        double s = xv[0] + xv[1] + xv[2] + xv[3];
        for (int m = 32; m > 0; m >>= 1) s += __shfl_xor(s, m, 64);
        double mu = s / 256.0, vs = 0.0;
#pragma unroll
        for (int i = 0; i < 4; i++) { double c = xv[i] - mu; vs += c * c; }
        for (int m = 32; m > 0; m >>= 1) vs += __shfl_xor(vs, m, 64);
        double inv = 1.0 / sqrt(vs / 256.0 + 1e-5);
#pragma unroll
        for (int i = 0; i < 4; i++) {
            int d = lane + 64 * i;
            float ff = (float)((xv[i] - mu) * inv * gv[i] + bv[i]);
            fh[(size_t)n * D_ + d] = (_Float16)ff;
        }
    } else {
        int k = (blockIdx.x - N_ / 4) * 4 + wv;
        double s = 0.0;
#pragma unroll
        for (int i = 0; i < 4; i++) {
            int d = lane + 64 * i;
            float v = w[(size_t)k * D_ + d];
            s += (double)v * (double)v;
            wh[(size_t)k * D_ + d] = (_Float16)v;
        }
        for (int m = 32; m > 0; m >>= 1) s += __shfl_xor(s, m, 64);
        if (lane == 0) { Bw[k] = s; Bwf[k] = (float)s; }
    }
}

// ---------------- Phase 1: f16 MFMA GEMM + fused top-2 -------------
// 1024 blocks x 256 thr (4 waves). Block = 128 rows x 256 codes.
// XCD-swizzled so the 4 chunks of one row-group share an XCD (L2 A-reuse).
__launch_bounds__(256, 3)
__global__ void k_phase1(const _Float16* __restrict__ fh, const _Float16* __restrict__ wh,
                         const float* __restrict__ Bwf, float* __restrict__ pq) {
    __shared__ __align__(16) _Float16 sA[2][128][32];
    __shared__ __align__(16) _Float16 sB[2][256][32];

    const int tid = threadIdx.x;
    const int lane = tid & 63;
    const int w = tid >> 6;        // wave 0..3
    const int l15 = lane & 15;
    const int g = lane >> 4;       // 0..3
    // swizzle: blocks with same id&7 go to same XCD (round-robin heuristic);
    // give each XCD 32 row-groups x 4 chunks so A tiles are L2-local.
    const int id = blockIdx.x;
    const int grp = (id & 7) * 32 + (id >> 5);       // 0..255
    const int chunk = (id >> 3) & 3;
    const int row0 = grp * 128;
    const int c0 = chunk * 256;

    const int srow = lane >> 2;
    const int scol = (lane & 3) * 8;
    const _Float16* ga0 = fh + (size_t)(row0 + w * 32 + srow) * 256 + scol;
    const _Float16* ga1 = ga0 + 16 * 256;
    const _Float16* gb0 = wh + (size_t)(c0 + w * 64 + srow) * 256 + scol;

    f32x4 acc[8][4];
#pragma unroll
    for (int a = 0; a < 8; a++)
#pragma unroll
        for (int b = 0; b < 4; b++) acc[a][b] = (f32x4){0.f, 0.f, 0.f, 0.f};

    GL16(ga0, &sA[0][w * 32][0]);
    GL16(ga1, &sA[0][w * 32 + 16][0]);
    GL16(gb0,         &sB[0][w * 64][0]);
    GL16(gb0 + 4096,  &sB[0][w * 64 + 16][0]);
    GL16(gb0 + 8192,  &sB[0][w * 64 + 32][0]);
    GL16(gb0 + 12288, &sB[0][w * 64 + 48][0]);

#pragma unroll
    for (int ks = 0; ks < 8; ks++) {
        __syncthreads();
        if (ks < 7) {
            const int buf = (ks + 1) & 1;
            const int eoff = (ks + 1) * 32;
            GL16(ga0 + eoff, &sA[buf][w * 32][0]);
            GL16(ga1 + eoff, &sA[buf][w * 32 + 16][0]);
            GL16(gb0 + eoff,         &sB[buf][w * 64][0]);
            GL16(gb0 + eoff + 4096,  &sB[buf][w * 64 + 16][0]);
            GL16(gb0 + eoff + 8192,  &sB[buf][w * 64 + 32][0]);
            GL16(gb0 + eoff + 12288, &sB[buf][w * 64 + 48][0]);
        }
        const int cur = ks & 1;
        f16x8 bfr[4];
#pragma unroll
        for (int fc = 0; fc < 4; fc++)
            bfr[fc] = *(const f16x8*)&sB[cur][w * 64 + fc * 16 + l15][g * 8];
#pragma unroll
        for (int fr = 0; fr < 8; fr++) {
            f16x8 af = *(const f16x8*)&sA[cur][fr * 16 + l15][g * 8];
#pragma unroll
            for (int fc = 0; fc < 4; fc++)
                acc[fr][fc] = __builtin_amdgcn_mfma_f32_16x16x32_f16(
                    af, bfr[fc], acc[fr][fc], 0, 0, 0);
        }
    }
    __syncthreads();

    float bwv[4];
#pragma unroll
    for (int fc = 0; fc < 4; fc++) bwv[fc] = Bwf[c0 + w * 64 + fc * 16 + l15];
    float* red = (float*)&sA[0][0][0];
#pragma unroll
    for (int fr = 0; fr < 8; fr++) {
#pragma unroll
        for (int r = 0; r < 4; r++) {
            float m1 = 3e38f, m2 = 3e38f; int c1 = 0x7fffffff;
#pragma unroll
            for (int fc = 0; fc < 4; fc++) {
                float sv = fmaf(-2.0f, acc[fr][fc][r], bwv[fc]);
                int c = c0 + w * 64 + fc * 16 + l15;
                if (sv < m1 || (sv == m1 && c < c1)) { m2 = m1; m1 = sv; c1 = c; }
                else if (sv < m2) m2 = sv;
            }
#pragma unroll
            for (int msk = 1; msk <= 8; msk <<= 1) {
                float om1 = __shfl_xor(m1, msk, 64);
                float om2 = __shfl_xor(m2, msk, 64);
                int   oc  = __shfl_xor(c1, msk, 64);
                if (om1 < m1 || (om1 == m1 && oc < c1)) {
                    m2 = (m1 < om2) ? m1 : om2; m1 = om1; c1 = oc;
                } else {
                    m2 = (om1 < m2) ? om1 : m2;
                }
            }
            if (l15 == 0) {
                int rl = fr * 16 + g * 4 + r;
                int base = (w * 128 + rl) * 3;
                red[base] = m1; red[base + 1] = m2; ((int*)red)[base + 2] = c1;
            }
        }
    }
    __syncthreads();
    if (tid < 128) {
        float M1 = 3e38f, M2 = 3e38f; int C1 = 0x7fffffff;
        for (int wv = 0; wv < 4; wv++) {
            int base = (wv * 128 + tid) * 3;
            float m1 = red[base], m2 = red[base + 1]; int c = ((int*)red)[base + 2];
            if (m1 < M1 || (m1 == M1 && c < C1)) {
                M2 = (M1 < m2) ? M1 : m2; M1 = m1; C1 = c;
            } else {
                M2 = (m1 < M2) ? m1 : M2;
            }
        }
        pq[chunk * N_ + row0 + tid] = M1;
        pq[4 * N_ + chunk * N_ + row0 + tid] = M2;
        ((int*)pq)[8 * N_ + chunk * N_ + row0 + tid] = C1;
    }
}

// ---------------- Phase 2: merge 4 chunk-partials + exact f64 verify ----
__global__ void k_phase2(const float* __restrict__ x, const float* __restrict__ gam,
                         const float* __restrict__ bet, const float* __restrict__ w,
                         const double* __restrict__ Bw, const float* __restrict__ pq,
                         double* __restrict__ sampled, int* __restrict__ idxf,
                         unsigned* __restrict__ slowC, int* __restrict__ slowL) {
    int lane = threadIdx.x & 63, wv = threadIdx.x >> 6;
    int n = blockIdx.x * 4 + wv;
    const float* pm1 = pq;
    const float* pm2 = pq + 4 * N_;
    const int*   pc1 = (const int*)pq + 8 * N_;
    float M1 = 3e38f, M2 = 3e38f; int C1 = 0x7fffffff;
#pragma unroll
    for (int c = 0; c < 4; c++) {
        float m1 = pm1[c * N_ + n], m2 = pm2[c * N_ + n]; int cc = pc1[c * N_ + n];
        if (m1 < M1 || (m1 == M1 && cc < C1)) {
            M2 = (M1 < m2) ? M1 : m2; M1 = m1; C1 = cc;
        } else {
            M2 = (m1 < M2) ? m1 : M2;
        }
    }
    if (M2 - M1 <= MARGIN) {
        if (lane == 0) { unsigned p = atomicAdd(slowC, 1u); slowL[p] = n; }
        return;
    }
    const float* row = x + (size_t)n * D_;
    double xv[4], gv[4], bv[4];
#pragma unroll
    for (int i = 0; i < 4; i++) {
        int d = lane + 64 * i;
        xv[i] = row[d]; gv[i] = gam[d]; bv[i] = bet[d];
    }
    double s = xv[0] + xv[1] + xv[2] + xv[3];
    for (int m = 32; m > 0; m >>= 1) s += __shfl_xor(s, m, 64);
    double mu = s / 256.0, vs = 0.0;
#pragma unroll
    for (int i = 0; i < 4; i++) { double c = xv[i] - mu; vs += c * c; }
    for (int m = 32; m > 0; m >>= 1) vs += __shfl_xor(vs, m, 64);
    double inv = 1.0 / sqrt(vs / 256.0 + 1e-5);
    double f[4], A = 0.0;
#pragma unroll
    for (int i = 0; i < 4; i++) {
        f[i] = (xv[i] - mu) * inv * gv[i] + bv[i];
        A += f[i] * f[i];
    }
    for (int m = 32; m > 0; m >>= 1) A += __shfl_xor(A, m, 64);

    const float* wr_ = w + (size_t)C1 * D_;
    double ss = 0.0;
#pragma unroll
    for (int i = 0; i < 4; i++) ss += f[i] * (double)wr_[lane + 64 * i];
    for (int m = 32; m > 0; m >>= 1) ss += __shfl_xor(ss, m, 64);
    if (lane == 0) { sampled[n] = (A + Bw[C1]) - 2.0 * ss; idxf[n] = C1; }
}

// ---------------- Slow rows: exact f64 full scan, lanes-over-codes -------------
// block per row (grid-stride). feats f64 in LDS (broadcast reads); lane owns a
// whole code => no per-code cross-lane reduce. w loads lane-strided 1KB, each
// 64B line reused by 4 consecutive float4 loads (L1-resident).
__launch_bounds__(256)
__global__ void k_slow(const float* __restrict__ x, const float* __restrict__ gam,
                       const float* __restrict__ bet, const float* __restrict__ w,
                       const double* __restrict__ Bw,
                       const int* __restrict__ slowL, const unsigned* __restrict__ slowC,
                       double* __restrict__ sampled, int* __restrict__ idxf) {
    __shared__ double sf[256];
    __shared__ double red8[8];
    __shared__ double bmW[4];
    __shared__ int    bcW[4];
    int tid = threadIdx.x, lane = tid & 63, wv = tid >> 6;
    int cnt = (int)*slowC;
    for (int it = blockIdx.x; it < cnt; it += gridDim.x) {
        int n = slowL[it];
        double xv = x[(size_t)n * D_ + tid];
        double gv = gam[tid], bv = bet[tid];
        double s = xv;
        for (int m = 32; m > 0; m >>= 1) s += __shfl_xor(s, m, 64);
        if (lane == 0) red8[wv] = s;
        __syncthreads();
        double mu = (red8[0] + red8[1] + red8[2] + red8[3]) / 256.0;
        double c = xv - mu;
        double v2 = c * c;
        for (int m = 32; m > 0; m >>= 1) v2 += __shfl_xor(v2, m, 64);
        __syncthreads();
        if (lane == 0) red8[wv] = v2;
        __syncthreads();
        double var = (red8[0] + red8[1] + red8[2] + red8[3]) / 256.0;
        double inv = 1.0 / sqrt(var + 1e-5);
        double f = c * inv * gv + bv;
        double a2 = f * f;
        for (int m = 32; m > 0; m >>= 1) a2 += __shfl_xor(a2, m, 64);
        if (lane == 0) red8[4 + wv] = a2;
        sf[tid] = f;
        __syncthreads();
        double A = red8[4] + red8[5] + red8[6] + red8[7];

        double bm = 1.0e300; int bc = 0x7fffffff;
        for (int r = 0; r < 4; r++) {
            int cc = r * 256 + wv * 64 + lane;
            const float* wr = w + (size_t)cc * D_;
            double acc = 0.0;
#pragma unroll 8
            for (int d4 = 0; d4 < 64; d4++) {
                float4 w4 = *(const float4*)(wr + d4 * 4);
                acc += sf[d4 * 4] * (double)w4.x + sf[d4 * 4 + 1] * (double)w4.y
                     + sf[d4 * 4 + 2] * (double)w4.z + sf[d4 * 4 + 3] * (double)w4.w;
            }
            double dist = (A + Bw[cc]) - 2.0 * acc;
            if (dist < bm) { bm = dist; bc = cc; }   // r ascending => lowest idx on tie
        }
        for (int m = 32; m > 0; m >>= 1) {
            double om = __shfl_xor(bm, m, 64);
            int    oc = __shfl_xor(bc, m, 64);
            if (om < bm || (om == bm && oc < bc)) { bm = om; bc = oc; }
        }
        if (lane == 0) { bmW[wv] = bm; bcW[wv] = bc; }
        __syncthreads();
        if (tid == 0) {
            double M = bmW[0]; int C = bcW[0];
            for (int i = 1; i < 4; i++)
                if (bmW[i] < M || (bmW[i] == M && bcW[i] < C)) { M = bmW[i]; C = bcW[i]; }
            sampled[n] = M; idxf[n] = C;
        }
        __syncthreads();
    }
}

// ---------------- stable argsort per batch row + enc gather -------------
__launch_bounds__(1024)
__global__ void k_sort(const double* __restrict__ sampled, const int* __restrict__ idxf,
                       int* __restrict__ enc) {
    __shared__ double val[1024];
    __shared__ int    sid[1024];
    int b = blockIdx.x, t = threadIdx.x;
    val[t] = sampled[(size_t)b * S_ + t];
    sid[t] = t;
    __syncthreads();
    for (int k = 2; k <= 1024; k <<= 1) {
        for (int j = k >> 1; j > 0; j >>= 1) {
            int p = t ^ j;
            if (p > t) {
                double v0 = val[t], v1 = val[p];
                int i0 = sid[t], i1 = sid[p];
                bool gtv = (v0 > v1) || (v0 == v1 && i0 > i1);
                bool asc = ((t & k) == 0);
                if (asc ? gtv : !gtv) {
                    val[t] = v1; val[p] = v0; sid[t] = i1; sid[p] = i0;
                }
            }
            __syncthreads();
        }
    }
    enc[(size_t)b * S_ + t] = idxf[sid[t]];   // faithful reference flat-index bug
}

// ---------------- gather: quantized out, idx out, counts, per-row loss -------------
__global__ void k_gather(const float* __restrict__ x, const float* __restrict__ w,
                         const int* __restrict__ enc, float* __restrict__ out,
                         unsigned* __restrict__ cnt, double* __restrict__ lossP) {
    int lane = threadIdx.x & 63, wv = threadIdx.x >> 6;
    int n = blockIdx.x * 4 + wv;
    int e = enc[n];
    const float* wr_ = w + (size_t)e * D_;
    const float* xr = x + (size_t)n * D_;
    float* qr = out + O_Q + (size_t)n * D_;
    double ls = 0.0;
#pragma unroll
    for (int i = 0; i < 4; i++) {
        int d = lane + 64 * i;
        float q = wr_[d], xv = xr[d];
        qr[d] = q;
        double df = (double)q - (double)xv;
        ls += df * df;
    }
    for (int m = 32; m > 0; m >>= 1) ls += __shfl_xor(ls, m, 64);
    if (lane == 0) {
        lossP[n] = ls;
        out[O_IDX + n] = (float)e;
        atomicAdd(&cnt[e], 1u);
    }
}

// ---------------- post: dw (enc-scan, no CSR) + new_weight + stats -------------
// blocks 0..1023: code k = blockIdx; thread t owns dim t.
// block 1024: loss / perplexity / NCS.
__launch_bounds__(256)
__global__ void k_post(const unsigned* __restrict__ cnt, const float* __restrict__ ema_cs,
                       const double* __restrict__ lossP, const int* __restrict__ enc,
                       const float* __restrict__ x, const float* __restrict__ ema_w,
                       float* __restrict__ out) {
    __shared__ double redd[24];
    __shared__ int mrows[1024];
    __shared__ int mcnt;
    __shared__ double ntot_s;
    int tid = threadIdx.x;

    // ntot = sum over codes of smoothed counts (all blocks need it)
    double part = 0.0;
    for (int i = tid; i < K_; i += 256)
        part += (double)(0.99f * ema_cs[i] + 0.01f * (float)cnt[i]);
    for (int m = 32; m > 0; m >>= 1) part += __shfl_xor(part, m, 64);
    if ((tid & 63) == 0) redd[tid >> 6] = part;
    __syncthreads();
    if (tid == 0) ntot_s = redd[0] + redd[1] + redd[2] + redd[3];
    __syncthreads();
    double ntot = ntot_s;

    if (blockIdx.x < K_) {
        int k = blockIdx.x;
        float cs0 = 0.99f * ema_cs[k] + 0.01f * (float)cnt[k];
        double csf = ((double)cs0 + 1e-5) / (ntot + 1024.0 * 1e-5) * ntot;
        float acc = 0.0f;
        if (tid == 0) mcnt = 0;
        __syncthreads();
        for (int tile = 0; tile < 32; tile++) {
            for (int j = tid; j < 1024; j += 256) {
                int r = tile * 1024 + j;
                if (enc[r] == k) { int p = atomicAdd(&mcnt, 1); mrows[p] = r; }
            }
            __syncthreads();
            int mc = mcnt;
            for (int j = 0; j < mc; j++) acc += x[(size_t)mrows[j] * D_ + tid];
            __syncthreads();
            if (tid == 0) mcnt = 0;
            __syncthreads();
        }
        size_t idx = (size_t)k * D_ + tid;
        float ne = 0.99f * ema_w[idx] + 0.01f * acc;
        out[O_NEW + idx] = ne;
        out[O_NW + idx] = ne / (float)csf;
    } else {
        // stats block
        for (int i = tid; i < K_; i += 256) {
            float cs0 = 0.99f * ema_cs[i] + 0.01f * (float)cnt[i];
            double c2 = ((double)cs0 + 1e-5) / (ntot + 1024.0 * 1e-5) * ntot;
            out[O_NCS + i] = (float)c2;
        }
        double ent = 0.0;
        for (int i = tid; i < K_; i += 256) {
            double p = (double)cnt[i] / 32768.0;
            ent += -p * log(p + 1e-10);
        }
        for (int m = 32; m > 0; m >>= 1) ent += __shfl_xor(ent, m, 64);
        if ((tid & 63) == 0) redd[8 + (tid >> 6)] = ent;
        double ls = 0.0;
        for (int i = tid; i < N_; i += 256) ls += lossP[i];
        for (int m = 32; m > 0; m >>= 1) ls += __shfl_xor(ls, m, 64);
        if ((tid & 63) == 0) redd[16 + (tid >> 6)] = ls;
        __syncthreads();
        if (tid == 0) {
            double e = redd[8] + redd[9] + redd[10] + redd[11];
            double l = redd[16] + redd[17] + redd[18] + redd[19];
            out[O_PERP] = (float)exp(e);
            out[O_LOSS] = (float)(1.25 * l / 8388608.0);
        }
    }
}

extern "C" void kernel_launch(void* const* d_in, const int* in_sizes, int n_in,
                              void* d_out, int out_size, void* d_ws, size_t ws_size,
                              hipStream_t stream) {
    (void)in_sizes; (void)n_in; (void)out_size; (void)ws_size;
    const float* x      = (const float*)d_in[0];
    const float* w      = (const float*)d_in[1];
    const float* ema_w  = (const float*)d_in[2];
    const float* ema_cs = (const float*)d_in[3];
    const float* g      = (const float*)d_in[4];
    const float* bt     = (const float*)d_in[5];
    float* out = (float*)d_out;
    char* ws = (char*)d_ws;

    _Float16* fh = (_Float16*)(ws + OFF_FH);
    _Float16* wh = (_Float16*)(ws + OFF_WH);
    double* Bw   = (double*)(ws + OFF_BW);
    float*  Bwf  = (float*)(ws + OFF_BWF);
    double* samp = (double*)(ws + OFF_SAMP);
    int*    idxf = (int*)(ws + OFF_IDXF);
    int*    enc  = (int*)(ws + OFF_ENC);
    unsigned* cnt = (unsigned*)(ws + OFF_CNT);
    unsigned* slowC = (unsigned*)(ws + OFF_SLOWC);
    int*    slowL = (int*)(ws + OFF_SLOWL);
    double* lossP = (double*)(ws + OFF_LOSSP);

    (void)hipMemsetAsync(ws + OFF_CNT, 0, 4160, stream);   // cnt + slowC

    k_pre<<<N_ / 4 + K_ / 4, 256, 0, stream>>>(x, g, bt, fh, w, Bw, Bwf, wh);
    k_phase1<<<1024, 256, 0, stream>>>(fh, wh, Bwf, out);  // partials in out-Q (dead region)
    k_phase2<<<N_ / 4, 256, 0, stream>>>(x, g, bt, w, Bw, out, samp, idxf, slowC, slowL);
    k_slow<<<2048, 256, 0, stream>>>(x, g, bt, w, Bw, slowL, slowC, samp, idxf);
    k_sort<<<B_, 1024, 0, stream>>>(samp, idxf, enc);
    k_gather<<<N_ / 4, 256, 0, stream>>>(x, w, enc, out, cnt, lossP);
    k_post<<<K_ + 1, 256, 0, stream>>>(cnt, ema_cs, lossP, enc, x, ema_w, out);
}